// Round 1
// baseline (555.340 us; speedup 1.0000x reference)
//
#include <hip/hip_runtime.h>

#define NTHREADS 256
#define MPT 4            // m-rows per thread per iteration (20 floats = 5x float4)

// One "SC layer" pass:  out[n,g] = act( sum_{m,k,f} Ld[n,m,k]*v[m,f]*P[f,g,k]
//                                      + Lu[n,m,k]*v[m,f]*Q[f,g,k] )
// Block n handles output row n; threads split the m dimension.
template <int FIN, int FOUT, bool ACT>
__global__ __launch_bounds__(NTHREADS)
void sc_pass(const float* __restrict__ Ld, const float* __restrict__ Lu,
             const float* __restrict__ v,   // [N, FIN]
             const float* __restrict__ P,   // [FIN, FOUT, K]
             const float* __restrict__ Q,   // [FIN, FOUT, K]
             float* __restrict__ out)       // [N, FOUT]
{
    constexpr int N = 4096, K = 5;
    constexpr int NA = K * FIN;            // accumulators per stack

    const int n   = blockIdx.x;
    const int tid = threadIdx.x;

    float accd[NA], accu[NA];
#pragma unroll
    for (int j = 0; j < NA; ++j) { accd[j] = 0.f; accu[j] = 0.f; }

    const float* __restrict__ ldrow = Ld + (size_t)n * N * K;
    const float* __restrict__ lurow = Lu + (size_t)n * N * K;

    for (int m0 = tid * MPT; m0 < N; m0 += NTHREADS * MPT) {
        float la[MPT * K], ua[MPT * K], sv[MPT * FIN];
        const float4* lp = reinterpret_cast<const float4*>(ldrow + (size_t)m0 * K);
        const float4* up = reinterpret_cast<const float4*>(lurow + (size_t)m0 * K);
        const float4* vp = reinterpret_cast<const float4*>(v + (size_t)m0 * FIN);
#pragma unroll
        for (int i = 0; i < MPT * K / 4; ++i) {   // 5 float4 per stack (16B aligned: 80B stride)
            reinterpret_cast<float4*>(la)[i] = lp[i];
            reinterpret_cast<float4*>(ua)[i] = up[i];
        }
#pragma unroll
        for (int i = 0; i < MPT * FIN / 4; ++i)   // FIN float4 (m0 multiple of 4 -> aligned)
            reinterpret_cast<float4*>(sv)[i] = vp[i];

#pragma unroll
        for (int mm = 0; mm < MPT; ++mm)
#pragma unroll
            for (int k = 0; k < K; ++k)
#pragma unroll
                for (int f = 0; f < FIN; ++f) {
                    accd[k * FIN + f] += la[mm * K + k] * sv[mm * FIN + f];
                    accu[k * FIN + f] += ua[mm * K + k] * sv[mm * FIN + f];
                }
    }

    // ---- block reduction: 2*NA scalars ----
    __shared__ float red[NTHREADS / 64][2 * NA];
    const int lane = tid & 63;
    const int wid  = tid >> 6;
#pragma unroll
    for (int j = 0; j < NA; ++j) {
        float vd = accd[j], vu = accu[j];
#pragma unroll
        for (int off = 32; off > 0; off >>= 1) {
            vd += __shfl_xor(vd, off);
            vu += __shfl_xor(vu, off);
        }
        if (lane == 0) { red[wid][j] = vd; red[wid][NA + j] = vu; }
    }
    __syncthreads();

    if (tid == 0) {
        float h[FOUT];
#pragma unroll
        for (int g = 0; g < FOUT; ++g) h[g] = 0.f;
#pragma unroll
        for (int k = 0; k < K; ++k)
#pragma unroll
            for (int f = 0; f < FIN; ++f) {
                float td = 0.f, tu = 0.f;
#pragma unroll
                for (int w = 0; w < NTHREADS / 64; ++w) {
                    td += red[w][k * FIN + f];
                    tu += red[w][NA + k * FIN + f];
                }
#pragma unroll
                for (int g = 0; g < FOUT; ++g) {
                    h[g] += td * P[(f * FOUT + g) * K + k]
                          + tu * Q[(f * FOUT + g) * K + k];
                }
            }
#pragma unroll
        for (int g = 0; g < FOUT; ++g) {
            float hv = h[g];
            out[(size_t)n * FOUT + g] = ACT ? (hv >= 0.f ? hv : 0.01f * hv) : hv;
        }
    }
}

extern "C" void kernel_launch(void* const* d_in, const int* in_sizes, int n_in,
                              void* d_out, int out_size, void* d_ws, size_t ws_size,
                              hipStream_t stream) {
    constexpr int N = 4096;
    const float* Ld = (const float*)d_in[0];
    const float* Lu = (const float*)d_in[1];
    const float* x  = (const float*)d_in[2];
    const float* P1 = (const float*)d_in[3];
    const float* Q1 = (const float*)d_in[4];
    const float* P2 = (const float*)d_in[5];
    const float* Q2 = (const float*)d_in[6];
    const float* P3 = (const float*)d_in[7];
    const float* Q3 = (const float*)d_in[8];
    float* out = (float*)d_out;

    float* s1 = (float*)d_ws;          // sigma(h1): [N,3]
    float* s2 = s1 + (size_t)N * 3;    // sigma(h2): [N,3]

    sc_pass<1, 3, true ><<<N, NTHREADS, 0, stream>>>(Ld, Lu, x,  P1, Q1, s1);
    sc_pass<3, 3, true ><<<N, NTHREADS, 0, stream>>>(Ld, Lu, s1, P2, Q2, s2);
    sc_pass<3, 1, false><<<N, NTHREADS, 0, stream>>>(Ld, Lu, s2, P3, Q3, out);
}

// Round 2
// 357.887 us; speedup vs baseline: 1.5517x; 1.5517x over previous
//
#include <hip/hip_runtime.h>

#define NTHREADS 256
#define KDIM 5
#define CHUNK_M 256
#define CHUNK_FLOATS (CHUNK_M * KDIM)   // 1280 floats = 5 KB per stack
#define NCHUNK (4096 / CHUNK_M)         // 16

typedef float __attribute__((address_space(3))) lds_f;
typedef const float __attribute__((address_space(1))) glb_f;

// out[n,g] = act( sum_{m,k,f} Ld[n,m,k]*v[m,f]*P[f,g,k] + Lu[n,m,k]*v[m,f]*Q[f,g,k] )
// Block n owns output row n. Stacks stream through double-buffered LDS via
// global_load_lds (lane-contiguous dword instructions), counted vmcnt pipeline.
template <int FIN, int FOUT, bool ACT>
__global__ __launch_bounds__(NTHREADS)
void sc_pass(const float* __restrict__ Ld, const float* __restrict__ Lu,
             const float* __restrict__ v,   // [N, FIN]
             const float* __restrict__ P,   // [FIN, FOUT, K]
             const float* __restrict__ Q,   // [FIN, FOUT, K]
             float* __restrict__ out)       // [N, FOUT]
{
    constexpr int N = 4096;
    constexpr int NA = KDIM * FIN;

    __shared__ float lds[2][2][CHUNK_FLOATS];          // [buf][stack][float] = 20 KB
    __shared__ float red[NTHREADS / 64][2 * NA];

    const int n    = blockIdx.x;
    const int tid  = threadIdx.x;
    const int wid  = tid >> 6;
    const int lane = tid & 63;

    const float* __restrict__ ldrow = Ld + (size_t)n * N * KDIM;
    const float* __restrict__ lurow = Lu + (size_t)n * N * KDIM;

    // Stage chunk c into buffer b. Per wave: 10 dword global_load_lds, each
    // lane-contiguous (256 B / 4 cache lines per instruction). LDS dest base
    // is wave-uniform; HW adds lane*4.
    auto stage = [&](int c, int b) {
#pragma unroll
        for (int i = 0; i < 5; ++i) {
            const int off = c * CHUNK_FLOATS + i * 256 + wid * 64 + lane;
            __builtin_amdgcn_global_load_lds((glb_f*)(ldrow + off),
                                             (lds_f*)&lds[b][0][i * 256 + wid * 64],
                                             4, 0, 0);
        }
#pragma unroll
        for (int i = 0; i < 5; ++i) {
            const int off = c * CHUNK_FLOATS + i * 256 + wid * 64 + lane;
            __builtin_amdgcn_global_load_lds((glb_f*)(lurow + off),
                                             (lds_f*)&lds[b][1][i * 256 + wid * 64],
                                             4, 0, 0);
        }
    };

    float accd[NA], accu[NA];
#pragma unroll
    for (int j = 0; j < NA; ++j) { accd[j] = 0.f; accu[j] = 0.f; }

    stage(0, 0);
    stage(1, 1);   // 20 loads outstanding

    for (int c = 0; c < NCHUNK; ++c) {
        // Wait for chunk c's 10 loads (keep chunk c+1's 10 in flight).
        if (c + 1 < NCHUNK) asm volatile("s_waitcnt vmcnt(10)" ::: "memory");
        else                asm volatile("s_waitcnt vmcnt(0)"  ::: "memory");
        __builtin_amdgcn_s_barrier();

        const int b = c & 1;
        const int m = c * CHUNK_M + tid;

        float sv[FIN];
#pragma unroll
        for (int f = 0; f < FIN; ++f) sv[f] = v[(size_t)m * FIN + f];

        // Thread t reads floats [t*5 .. t*5+4]: stride 5 is coprime with 32
        // banks -> 2 lanes/bank -> conflict-free.
        float ldv[KDIM], luv[KDIM];
#pragma unroll
        for (int q = 0; q < KDIM; ++q) {
            ldv[q] = lds[b][0][tid * KDIM + q];
            luv[q] = lds[b][1][tid * KDIM + q];
        }
#pragma unroll
        for (int k = 0; k < KDIM; ++k)
#pragma unroll
            for (int f = 0; f < FIN; ++f) {
                accd[k * FIN + f] += ldv[k] * sv[f];
                accu[k * FIN + f] += luv[k] * sv[f];
            }

        asm volatile("" ::: "memory");           // compiler fence: no ds_read sinking
        __builtin_amdgcn_s_barrier();            // all waves done reading buf b
        if (c + 2 < NCHUNK) stage(c + 2, b);
    }

    // ---- block reduction: 2*NA scalars ----
#pragma unroll
    for (int j = 0; j < NA; ++j) {
        float vd = accd[j], vu = accu[j];
#pragma unroll
        for (int off = 32; off > 0; off >>= 1) {
            vd += __shfl_xor(vd, off);
            vu += __shfl_xor(vu, off);
        }
        if (lane == 0) { red[wid][j] = vd; red[wid][NA + j] = vu; }
    }
    __syncthreads();

    if (tid == 0) {
        float h[FOUT];
#pragma unroll
        for (int g = 0; g < FOUT; ++g) h[g] = 0.f;
#pragma unroll
        for (int k = 0; k < KDIM; ++k)
#pragma unroll
            for (int f = 0; f < FIN; ++f) {
                float td = 0.f, tu = 0.f;
#pragma unroll
                for (int w = 0; w < NTHREADS / 64; ++w) {
                    td += red[w][k * FIN + f];
                    tu += red[w][NA + k * FIN + f];
                }
#pragma unroll
                for (int g = 0; g < FOUT; ++g) {
                    h[g] += td * P[(f * FOUT + g) * KDIM + k]
                          + tu * Q[(f * FOUT + g) * KDIM + k];
                }
            }
#pragma unroll
        for (int g = 0; g < FOUT; ++g) {
            float hv = h[g];
            out[(size_t)n * FOUT + g] = ACT ? (hv >= 0.f ? hv : 0.01f * hv) : hv;
        }
    }
}

extern "C" void kernel_launch(void* const* d_in, const int* in_sizes, int n_in,
                              void* d_out, int out_size, void* d_ws, size_t ws_size,
                              hipStream_t stream) {
    constexpr int N = 4096;
    const float* Ld = (const float*)d_in[0];
    const float* Lu = (const float*)d_in[1];
    const float* x  = (const float*)d_in[2];
    const float* P1 = (const float*)d_in[3];
    const float* Q1 = (const float*)d_in[4];
    const float* P2 = (const float*)d_in[5];
    const float* Q2 = (const float*)d_in[6];
    const float* P3 = (const float*)d_in[7];
    const float* Q3 = (const float*)d_in[8];
    float* out = (float*)d_out;

    float* s1 = (float*)d_ws;          // sigma(h1): [N,3]
    float* s2 = s1 + (size_t)N * 3;    // sigma(h2): [N,3]

    sc_pass<1, 3, true ><<<N, NTHREADS, 0, stream>>>(Ld, Lu, x,  P1, Q1, s1);
    sc_pass<3, 3, true ><<<N, NTHREADS, 0, stream>>>(Ld, Lu, s1, P2, Q2, s2);
    sc_pass<3, 1, false><<<N, NTHREADS, 0, stream>>>(Ld, Lu, s2, P3, Q3, out);
}